// Round 8
// baseline (3471.022 us; speedup 1.0000x reference)
//
#include <hip/hip_runtime.h>
#include <hip/hip_bf16.h>

#define S_TOK 8192
#define DM    2048
#define DFF   8192
#define NE    8
#define CAP   1024

typedef __bf16 bf16_t;
typedef __bf16 bf16x8 __attribute__((ext_vector_type(8)));
typedef float  f32x4  __attribute__((ext_vector_type(4)));

__device__ __forceinline__ void load_lds16(const void* g, void* l) {
    __builtin_amdgcn_global_load_lds((const __attribute__((address_space(1))) void*)g,
                                     (__attribute__((address_space(3))) void*)l,
                                     16, 0, 0);
}

// ---------------- Kernel 1: gate logits + argmax — one wave per token ---------------
__global__ __launch_bounds__(256) void gate_argmax(const float* __restrict__ x,
                                                   const float* __restrict__ wg,
                                                   int* __restrict__ eidx) {
    int lane = threadIdx.x & 63, wv = threadIdx.x >> 6;
    int s = blockIdx.x * 4 + wv;
    const float* row = x + (size_t)s * DM;
    float acc[8] = {0.f,0.f,0.f,0.f,0.f,0.f,0.f,0.f};
    for (int kb = 0; kb < DM; kb += 256) {
        int k0 = kb + lane * 4;
        float4 xv = *(const float4*)(row + k0);
        const float* wr = wg + (size_t)k0 * NE;
        float xs[4] = {xv.x, xv.y, xv.z, xv.w};
#pragma unroll
        for (int c = 0; c < 4; ++c) {
            float4 w0 = *(const float4*)(wr + c * 8);
            float4 w1 = *(const float4*)(wr + c * 8 + 4);
            acc[0] += xs[c] * w0.x; acc[1] += xs[c] * w0.y;
            acc[2] += xs[c] * w0.z; acc[3] += xs[c] * w0.w;
            acc[4] += xs[c] * w1.x; acc[5] += xs[c] * w1.y;
            acc[6] += xs[c] * w1.z; acc[7] += xs[c] * w1.w;
        }
    }
#pragma unroll
    for (int off = 32; off > 0; off >>= 1)
#pragma unroll
        for (int e = 0; e < 8; ++e) acc[e] += __shfl_xor(acc[e], off, 64);
    if (lane == 0) {
        float best = acc[0]; int bi = 0;
#pragma unroll
        for (int e = 1; e < 8; ++e) if (acc[e] > best) { best = acc[e]; bi = e; }
        eidx[s] = bi;
    }
}

// ---------------- Kernel 2: slot assignment — single wave, prefetch-pipelined -------
__global__ __launch_bounds__(64) void scatter_slots(const int* __restrict__ eidx,
                                                    int* __restrict__ srcOf) {
    int lane = threadIdx.x;
    unsigned long long below = (lane == 0) ? 0ull : ((1ull << lane) - 1ull);
    for (int i = lane; i < NE * CAP; i += 64) srcOf[i] = -1;

    int cnt[NE] = {0,0,0,0,0,0,0,0};
    int e_cur = eidx[lane];
    for (int it = 0; it < S_TOK / 64; ++it) {
        int e_nxt = (it < S_TOK / 64 - 1) ? eidx[(it + 1) * 64 + lane] : 0;
        int s = it * 64 + lane;
#pragma unroll
        for (int ex = 0; ex < NE; ++ex) {
            unsigned long long m = __ballot(e_cur == ex);
            if (e_cur == ex) {
                int loc = cnt[ex] + __popcll(m & below);
                if (loc < CAP) srcOf[ex * CAP + loc] = s;
            }
            cnt[ex] += __popcll(m);
        }
        e_cur = e_nxt;
    }
}

// ---------------- Kernel 3: gather + f32->bf16, pre-swizzled A images (BM=512) ------
// A image per (e, mt in {0,1}, kt in 0..63): 32 KB = [512 rows][32 k] bf16.
// byte = r*64 + ((s ^ ((r>>1)&3))<<4), s = k-chunk (8 bf16).  gload_lds copies linearly.
__global__ __launch_bounds__(256) void pack_rows(const float* __restrict__ x,
                                                 const int* __restrict__ srcOf,
                                                 char* __restrict__ abuf) {
    int slot = blockIdx.x;               // e*1024 + c
    int e = slot >> 10, c = slot & 1023;
    int mt = c >> 9, r = c & 511;
    int src = srcOf[slot];
    int tid = threadIdx.x;
    int kt = tid >> 2, s = tid & 3;      // kt 0..63, s 0..3
    bf16x8 v = {};
    if (src >= 0) {
        const float4* p = (const float4*)(x + (size_t)src * DM + kt * 32 + s * 8);
        float4 a = p[0], b = p[1];
        v = bf16x8{(bf16_t)a.x,(bf16_t)a.y,(bf16_t)a.z,(bf16_t)a.w,
                   (bf16_t)b.x,(bf16_t)b.y,(bf16_t)b.z,(bf16_t)b.w};
    }
    size_t img = ((size_t)((e * 2 + mt) * 64 + kt)) << 15;
    int off = r * 64 + ((s ^ ((r >> 1) & 3)) << 4);
    *(bf16x8*)(abuf + img + off) = v;
}

// ---------------- Kernel 4: 512x256 GEMM, 1024 thr, A gload_lds + B f32 in-loop -----
// LDS: A dbuf 2x32KB @0, B dbuf 2x32KB @65536. B tile: [256 n][64 k] bf16 rows 128B,
// slot o (16B, k=o*8..+7) at (o ^ ((n>>1)&7))*16.
__global__ __launch_bounds__(1024) void moe_gemm(const char* __restrict__ abuf,
                                                 const float* __restrict__ we,
                                                 const float* __restrict__ be,
                                                 float* __restrict__ out) {
    __shared__ uint4 smem4[131072 / 16];
    char* smem = (char*)smem4;

    int bid = blockIdx.x;
    int e  = bid & 7;                   // expert == XCD
    int r  = bid >> 3;
    int mt = r & 1;                     // 2 m-tiles of 512
    int nt = r >> 1;                    // 32 n-tiles of 256
    int tid = threadIdx.x, lane = tid & 63, wv = tid >> 6;
    int wm = wv >> 2, wn = wv & 3;      // 4x4 wave grid -> 128x64 per wave
    int lr = lane & 15, g = lane >> 4;

    const char* aImg = abuf + (((size_t)((e * 2 + mt) * 64)) << 15);
    // B staging: thread (kq = tid>>6, n4 = tid&63): rows kq*4..+3, cols n4*4..+3
    int kq = tid >> 6, n4 = tid & 63;
    const float* bBase = we + (size_t)e * DM * DFF + (size_t)nt * 256 + n4 * 4;

    f32x4 acc[8][4] = {};
    float bs[16];
    int colA = (g ^ ((lr >> 1) & 3)) << 4;

    auto issueA = [&](int idx, int buf) {       // 32KB A sub-tile (K=32)
        const char* src = aImg + ((size_t)idx << 15) + tid * 16;
        char* dst = smem + buf * 32768 + tid * 16;
        load_lds16(src, dst);
        load_lds16(src + 16384, dst + 16384);
    };
    auto issueB = [&](int kt2) {                // 4 float4 -> bs
        const float* bp = bBase + (size_t)(kt2 * 64 + kq * 4) * DFF;
#pragma unroll
        for (int i = 0; i < 4; ++i) {
            float4 t = *(const float4*)(bp + (size_t)i * DFF);
            bs[i*4+0] = t.x; bs[i*4+1] = t.y; bs[i*4+2] = t.z; bs[i*4+3] = t.w;
        }
    };
    auto writeB = [&](char* bL) {               // 4 x uint2 (4 k as bf16)
#pragma unroll
        for (int j = 0; j < 4; ++j) {
            int n = n4 * 4 + j;
            ushort w[4];
#pragma unroll
            for (int i = 0; i < 4; ++i) {
                bf16_t b = (bf16_t)bs[i * 4 + j];
                w[i] = __builtin_bit_cast(unsigned short, b);
            }
            uint2 pk = { (unsigned)w[0] | ((unsigned)w[1] << 16),
                         (unsigned)w[2] | ((unsigned)w[3] << 16) };
            int off = n * 128 + ((((kq >> 1) ^ ((n >> 1) & 7))) << 4) + (kq & 1) * 8;
            *(uint2*)(bL + off) = pk;
        }
    };

    // prologue: B(0) loaded+written to b-buf0; A(0) staged to a-buf0
    issueA(0, 0);
    issueB(0);
    writeB(smem + 65536);
    __syncthreads();

    for (int kt2 = 0; kt2 < 32; ++kt2) {
        bool nl = (kt2 < 31);
        const char* bC = smem + 65536 + (kt2 & 1) * 32768;
        char* bN = smem + 65536 + ((kt2 + 1) & 1) * 32768;
        if (nl) issueB(kt2 + 1);
#pragma unroll
        for (int h = 0; h < 2; ++h) {
            int aIdx = kt2 * 2 + h;
            const char* aC = smem + (aIdx & 1) * 32768;
            if (aIdx + 1 < 64) issueA(aIdx + 1, (aIdx + 1) & 1);
            __builtin_amdgcn_sched_barrier(0);   // staging issues stay at phase top

            bf16x8 af[8];
#pragma unroll
            for (int mf = 0; mf < 8; ++mf)
                af[mf] = *(const bf16x8*)(aC + (wm * 128 + mf * 16 + lr) * 64 + colA);
            bf16x8 bfr[4];
#pragma unroll
            for (int nf = 0; nf < 4; ++nf) {
                int n = wn * 64 + nf * 16 + lr;
                int o = h * 4 + g;
                bfr[nf] = *(const bf16x8*)(bC + n * 128 + ((o ^ ((n >> 1) & 7)) << 4));
            }
#pragma unroll
            for (int nf = 0; nf < 4; ++nf) {
                __builtin_amdgcn_s_setprio(1);
#pragma unroll
                for (int mf = 0; mf < 8; ++mf)
                    acc[mf][nf] = __builtin_amdgcn_mfma_f32_16x16x32_bf16(
                        af[mf], bfr[nf], acc[mf][nf], 0, 0, 0);
                __builtin_amdgcn_s_setprio(0);
            }
            if (h == 1 && nl) writeB(bN);
            __syncthreads();
        }
    }

    // epilogue: C/D layout col=lane&15, row=(lane>>4)*4+q
    int orow0 = e * CAP + mt * 512 + wm * 128 + g * 4;
    int ocol0 = nt * 256 + wn * 64 + lr;
#pragma unroll
    for (int nf = 0; nf < 4; ++nf) {
        int oc = ocol0 + nf * 16;
        float bias = be[(size_t)e * DFF + oc];
#pragma unroll
        for (int mf = 0; mf < 8; ++mf) {
            int orow = orow0 + mf * 16;
#pragma unroll
            for (int q = 0; q < 4; ++q)
                out[(size_t)(orow + q) * DFF + oc] = acc[mf][nf][q] + bias;
        }
    }
}

// ---------------- launcher ----------------------------------------------------------
extern "C" void kernel_launch(void* const* d_in, const int* in_sizes, int n_in,
                              void* d_out, int out_size, void* d_ws, size_t ws_size,
                              hipStream_t stream) {
    const float* x  = (const float*)d_in[0];
    const float* wg = (const float*)d_in[1];
    const float* we = (const float*)d_in[2];
    const float* be = (const float*)d_in[3];
    float* out = (float*)d_out;

    size_t need = 65536 + (size_t)32 * 1048576;   // 64 KB meta + 32 MB abuf
    if (ws_size < need) return;

    int* eidx  = (int*)d_ws;
    int* srcOf = eidx + S_TOK;
    char* abuf = (char*)d_ws + 65536;

    gate_argmax<<<S_TOK / 4, 256, 0, stream>>>(x, wg, eidx);
    scatter_slots<<<1, 64, 0, stream>>>(eidx, srcOf);
    pack_rows<<<S_TOK, 256, 0, stream>>>(x, srcOf, abuf);
    moe_gemm<<<NE * 2 * 32, 1024, 0, stream>>>(abuf, we, be, out);
}

// Round 9
// 587.413 us; speedup vs baseline: 5.9090x; 5.9090x over previous
//
#include <hip/hip_runtime.h>
#include <hip/hip_bf16.h>

#define S_TOK 8192
#define DM    2048
#define DFF   8192
#define NE    8
#define CAP   1024

typedef __bf16 bf16_t;
typedef __bf16 bf16x8 __attribute__((ext_vector_type(8)));
typedef float  f32x4  __attribute__((ext_vector_type(4)));

__device__ __forceinline__ void load_lds16(const void* g, void* l) {
    __builtin_amdgcn_global_load_lds((const __attribute__((address_space(1))) void*)g,
                                     (__attribute__((address_space(3))) void*)l,
                                     16, 0, 0);
}

// ---------------- Kernel 1: gate logits + argmax — one wave per token ---------------
__global__ __launch_bounds__(256) void gate_argmax(const float* __restrict__ x,
                                                   const float* __restrict__ wg,
                                                   int* __restrict__ eidx) {
    int lane = threadIdx.x & 63, wv = threadIdx.x >> 6;
    int s = blockIdx.x * 4 + wv;
    const float* row = x + (size_t)s * DM;
    float acc[8] = {0.f,0.f,0.f,0.f,0.f,0.f,0.f,0.f};
    for (int kb = 0; kb < DM; kb += 256) {
        int k0 = kb + lane * 4;
        float4 xv = *(const float4*)(row + k0);
        const float* wr = wg + (size_t)k0 * NE;
        float xs[4] = {xv.x, xv.y, xv.z, xv.w};
#pragma unroll
        for (int c = 0; c < 4; ++c) {
            float4 w0 = *(const float4*)(wr + c * 8);
            float4 w1 = *(const float4*)(wr + c * 8 + 4);
            acc[0] += xs[c] * w0.x; acc[1] += xs[c] * w0.y;
            acc[2] += xs[c] * w0.z; acc[3] += xs[c] * w0.w;
            acc[4] += xs[c] * w1.x; acc[5] += xs[c] * w1.y;
            acc[6] += xs[c] * w1.z; acc[7] += xs[c] * w1.w;
        }
    }
#pragma unroll
    for (int off = 32; off > 0; off >>= 1)
#pragma unroll
        for (int e = 0; e < 8; ++e) acc[e] += __shfl_xor(acc[e], off, 64);
    if (lane == 0) {
        float best = acc[0]; int bi = 0;
#pragma unroll
        for (int e = 1; e < 8; ++e) if (acc[e] > best) { best = acc[e]; bi = e; }
        eidx[s] = bi;
    }
}

// ---------------- Kernel 2: slot assignment — single wave, prefetch-pipelined -------
__global__ __launch_bounds__(64) void scatter_slots(const int* __restrict__ eidx,
                                                    int* __restrict__ srcOf) {
    int lane = threadIdx.x;
    unsigned long long below = (lane == 0) ? 0ull : ((1ull << lane) - 1ull);
    for (int i = lane; i < NE * CAP; i += 64) srcOf[i] = -1;

    int cnt[NE] = {0,0,0,0,0,0,0,0};
    int e_cur = eidx[lane];
    for (int it = 0; it < S_TOK / 64; ++it) {
        int e_nxt = (it < S_TOK / 64 - 1) ? eidx[(it + 1) * 64 + lane] : 0;
        int s = it * 64 + lane;
#pragma unroll
        for (int ex = 0; ex < NE; ++ex) {
            unsigned long long m = __ballot(e_cur == ex);
            if (e_cur == ex) {
                int loc = cnt[ex] + __popcll(m & below);
                if (loc < CAP) srcOf[ex * CAP + loc] = s;
            }
            cnt[ex] += __popcll(m);
        }
        e_cur = e_nxt;
    }
}

// ---------------- Kernel 3: gather + f32->bf16, UNIT-ordered pre-swizzled A images --
// A image per (e,mt,kt): 32 KB = [unit0: rows m bit6==0][unit1: bit6==1],
// within-unit pos = ((m>>7)<<6)|(m&63), byte = pos*128 + ((kbyte)^((m&7)<<4)).
__global__ __launch_bounds__(256) void pack_rows(const float* __restrict__ x,
                                                 const int* __restrict__ srcOf,
                                                 char* __restrict__ abuf) {
    int slot = blockIdx.x;               // e*1024 + c
    int e = slot >> 10, c = slot & 1023;
    int mt = c >> 8, m = c & 255;
    int src = srcOf[slot];
    int tid = threadIdx.x;
    int kt = tid >> 3, kg = tid & 7;     // kt 0..31, kg 0..7
    bf16x8 v = {};
    if (src >= 0) {
        const float4* p = (const float4*)(x + (size_t)src * DM + kt * 64 + kg * 8);
        float4 a = p[0], b = p[1];
        v = bf16x8{(bf16_t)a.x,(bf16_t)a.y,(bf16_t)a.z,(bf16_t)a.w,
                   (bf16_t)b.x,(bf16_t)b.y,(bf16_t)b.z,(bf16_t)b.w};
    }
    size_t img = ((size_t)((e * 4 + mt) * 32 + kt)) << 15;
    int u = (m >> 6) & 1;
    int pos = ((m >> 7) << 6) | (m & 63);
    int off = u * 16384 + pos * 128 + ((kg * 16) ^ ((m & 7) << 4));
    *(bf16x8*)(abuf + img + off) = v;
}

// ---- Kernel 4: 256x256x64, f32-B in-loop cvt, 4-phase register-prefetch pipeline ---
// LDS half (64KB): [A0@0][A1@16K][B0@32K][B1@48K]. B units: u=(n>>5)&1,
// pos=((n>>6)<<5)|(n&31); phys chunk = logical ^ ((n&7)^((n>>3)&7)).
__global__ __launch_bounds__(512, 2) void moe_gemm(const char* __restrict__ abuf,
                                                   const float* __restrict__ we,
                                                   const float* __restrict__ be,
                                                   float* __restrict__ out) {
    __shared__ uint4 smem4[131072 / 16];
    char* smem = (char*)smem4;

    int bid = blockIdx.x;
    int e  = bid & 7;                   // expert == XCD
    int r  = bid >> 3;
    int mt = r & 3;
    int nt = r >> 2;
    int tid = threadIdx.x, lane = tid & 63, wv = tid >> 6;
    int wm = wv >> 2, wn = wv & 3;      // 2x4 wave grid -> 128x64 per wave
    int lr = lane & 15, g = lane >> 4;

    const char* aI = abuf + (((size_t)((e * 4 + mt) * 32)) << 15);
    const float* bBase = we + (size_t)e * DM * DFF + (size_t)nt * 256 + lane * 4;
    int stOff = tid * 16;

    f32x4 acc[8][4] = {};
    bf16x8 af[4][2];                    // holds A0 then A1 (reloaded mid-tile)
    bf16x8 bf0[2][2], bf1[2][2];
    float  bs[16];

    int colx[2] = { ((0 * 4 + g) ^ (lr & 7)) << 4, ((1 * 4 + g) ^ (lr & 7)) << 4 };
    int posA = (wm * 64 + lr) * 128;

    auto stageA = [&](int kt, int u) {
        const char* src = aI + ((size_t)kt << 15) + u * 16384 + stOff;
        char* dst = smem + (kt & 1) * 65536 + u * 16384 + stOff;
        load_lds16(src, dst);
        load_lds16(src + 8192, dst + 8192);
    };
    auto issueB = [&](int kt, int h) {
        const float* bp = bBase + (size_t)(kt * 64 + wv * 8 + h * 4) * DFF;
#pragma unroll
        for (int j = 0; j < 4; ++j) {
            float4 t = *(const float4*)(bp + (size_t)j * DFF);
            bs[j*4+0] = t.x; bs[j*4+1] = t.y; bs[j*4+2] = t.z; bs[j*4+3] = t.w;
        }
    };
    auto writeB = [&](int buf, int h) {
        char* bL = smem + buf * 65536 + 32768;
#pragma unroll
        for (int i = 0; i < 4; ++i) {
            int n = lane * 4 + i;
            ushort w[4];
#pragma unroll
            for (int j = 0; j < 4; ++j) {
                bf16_t b = (bf16_t)bs[j * 4 + i];
                w[j] = __builtin_bit_cast(unsigned short, b);
            }
            uint2 pk = { (unsigned)w[0] | ((unsigned)w[1] << 16),
                         (unsigned)w[2] | ((unsigned)w[3] << 16) };
            int u = (n >> 5) & 1;
            int pos = ((n >> 6) << 5) | (n & 31);
            int swz = (n & 7) ^ ((n >> 3) & 7);
            *(uint2*)(bL + u * 16384 + pos * 128 + (((unsigned)(wv ^ swz)) << 4) + h * 8) = pk;
        }
    };

#define RD_AF(U, TB)                                                                 \
    _Pragma("unroll")                                                                \
    for (int mf = 0; mf < 4; ++mf) {                                                 \
        af[mf][0] = *(const bf16x8*)((TB) + (U)*16384 + posA + mf * 2048 + colx[0]); \
        af[mf][1] = *(const bf16x8*)((TB) + (U)*16384 + posA + mf * 2048 + colx[1]); \
    }
#define RD_BF(DST, NH, TB)                                                           \
    _Pragma("unroll")                                                                \
    for (int nf = 0; nf < 2; ++nf) {                                                 \
        int n_ = wn * 64 + (NH) * 32 + nf * 16 + lr;                                 \
        int xb_ = (n_ & 7) ^ ((n_ >> 3) & 7);                                        \
        int pb_ = (wn * 32 + nf * 16 + lr) * 128 + (NH) * 16384 + 32768;             \
        DST[nf][0] = *(const bf16x8*)((TB) + pb_ + (((0 * 4 + g) ^ xb_) << 4));      \
        DST[nf][1] = *(const bf16x8*)((TB) + pb_ + (((1 * 4 + g) ^ xb_) << 4));      \
    }
#define CLUSTER(MH, NH, BV)                                                          \
    __builtin_amdgcn_s_setprio(1);                                                   \
    _Pragma("unroll")                                                                \
    for (int mf = 0; mf < 4; ++mf)                                                   \
        _Pragma("unroll")                                                            \
        for (int nf = 0; nf < 2; ++nf)                                               \
            _Pragma("unroll")                                                        \
            for (int kk = 0; kk < 2; ++kk)                                           \
                acc[(MH)*4 + mf][(NH)*2 + nf] =                                      \
                    __builtin_amdgcn_mfma_f32_16x16x32_bf16(                         \
                        af[mf][kk], BV[nf][kk],                                      \
                        acc[(MH)*4 + mf][(NH)*2 + nf], 0, 0, 0);                     \
    __builtin_amdgcn_s_setprio(0);
#define LGKM(N) asm volatile("s_waitcnt lgkmcnt(" #N ")" ::: "memory");              \
                __builtin_amdgcn_sched_barrier(0);
#define VMC(N)  asm volatile("s_waitcnt vmcnt(" #N ")" ::: "memory");                \
                __builtin_amdgcn_sched_barrier(0);
#define BARR()  __builtin_amdgcn_s_barrier(); __builtin_amdgcn_sched_barrier(0);

    // ---- prologue: tile 0 fully staged into half 0 ----
    issueB(0, 0);                       // bs <- B(0,h0)            [4 vm]
    stageA(0, 0); stageA(0, 1);         // A(0) -> LDS              [4 vm]
    VMC(4);                             // bs(h0) landed
    writeB(0, 0);
    issueB(0, 1);                       // bs <- B(0,h1)
    VMC(0);                             // A(0) + bs(h1) landed
    writeB(0, 1);
    LGKM(0);                            // ds_writes drained
    BARR();
    RD_AF(0, smem);                     // af <- A0(0)              [8 ds]

    for (int t = 0; t < 32; ++t) {
        const char* tb = smem + (t & 1) * 65536;
        int nxt = (t + 1) & 1;
        bool nl = (t < 31);

        // ---- P0 top: read bf0,bf1(t); prefetch next tile's B-h0 + A units ----
        RD_BF(bf0, 0, tb);              // [4 ds]
        RD_BF(bf1, 1, tb);              // [4 ds]
        if (nl) {
            issueB(t + 1, 0);           // [4 vm]  (FIFO first)
            stageA(t + 1, 0); stageA(t + 1, 1);   // [4 vm]
        }
        BARR();                         // b1(P0)
        LGKM(4);                        // retire af(A0)+bf0; bf1 may fly
        CLUSTER(0, 0, bf0);
        BARR();                         // b2(P0)

        // ---- P1: no top reads ----
        BARR();                         // b1(P1)
        LGKM(0);                        // bf1 done (1 phase old)
        CLUSTER(0, 1, bf1);
        RD_AF(1, tb);                   // af <- A1(t)   [8 ds, post-MFMA]
        BARR();                         // b2(P1)

        // ---- P2 top: retire bs(h0), write it; issue h1 ----
        VMC(4);                         // bs(h0) landed (A' still in flight)
        if (nl) { writeB(nxt, 0); issueB(t + 1, 1); }
        BARR();                         // b1(P2)
        LGKM(4);                        // retire af(A1) reads; h0 writes may fly
        CLUSTER(1, 0, bf0);
        VMC(4);                         // retire A'(t+1) gloads (bs h1 in flight)
        BARR();                         // b2(P2)

        // ---- P3 top: retire bs(h1), write it ----
        VMC(0);                         // bs(h1) landed
        if (nl) writeB(nxt, 1);
        BARR();                         // b1(P3)
        CLUSTER(1, 1, bf1);
        LGKM(0);                        // drain h0+h1 writes before publishing
        if (nl) { RD_AF(0, smem + nxt * 65536); }   // af <- A0(t+1)  [8 ds]
        BARR();                         // b2(P3)
    }

    // epilogue: C/D layout col=lane&15, row=(lane>>4)*4+q
    int orow0 = e * CAP + mt * 256 + wm * 128 + g * 4;
    int ocol0 = nt * 256 + wn * 64 + lr;
#pragma unroll
    for (int nf = 0; nf < 4; ++nf) {
        int oc = ocol0 + nf * 16;
        float bias = be[(size_t)e * DFF + oc];
#pragma unroll
        for (int mf = 0; mf < 8; ++mf) {
            int orow = orow0 + mf * 16;
#pragma unroll
            for (int q = 0; q < 4; ++q)
                out[(size_t)(orow + q) * DFF + oc] = acc[mf][nf][q] + bias;
        }
    }
#undef RD_AF
#undef RD_BF
#undef CLUSTER
#undef LGKM
#undef VMC
#undef BARR
}

// ---------------- launcher ----------------------------------------------------------
extern "C" void kernel_launch(void* const* d_in, const int* in_sizes, int n_in,
                              void* d_out, int out_size, void* d_ws, size_t ws_size,
                              hipStream_t stream) {
    const float* x  = (const float*)d_in[0];
    const float* wg = (const float*)d_in[1];
    const float* we = (const float*)d_in[2];
    const float* be = (const float*)d_in[3];
    float* out = (float*)d_out;

    size_t need = 65536 + (size_t)32 * 1048576;   // 64 KB meta + 32 MB abuf
    if (ws_size < need) return;

    int* eidx  = (int*)d_ws;
    int* srcOf = eidx + S_TOK;
    char* abuf = (char*)d_ws + 65536;

    gate_argmax<<<S_TOK / 4, 256, 0, stream>>>(x, wg, eidx);
    scatter_slots<<<1, 64, 0, stream>>>(eidx, srcOf);
    pack_rows<<<S_TOK, 256, 0, stream>>>(x, srcOf, abuf);
    moe_gemm<<<NE * 4 * 32, 512, 0, stream>>>(abuf, we, be, out);
}

// Round 11
// 576.145 us; speedup vs baseline: 6.0246x; 1.0196x over previous
//
#include <hip/hip_runtime.h>
#include <hip/hip_bf16.h>

#define S_TOK 8192
#define DM    2048
#define DFF   8192
#define NE    8
#define CAP   1024

typedef __bf16 bf16_t;
typedef __bf16 bf16x8 __attribute__((ext_vector_type(8)));
typedef float  f32x4  __attribute__((ext_vector_type(4)));

__device__ __forceinline__ void load_lds16(const void* g, void* l) {
    __builtin_amdgcn_global_load_lds((const __attribute__((address_space(1))) void*)g,
                                     (__attribute__((address_space(3))) void*)l,
                                     16, 0, 0);
}

// ---------------- Kernel 1: gate logits + argmax — one wave per token ---------------
__global__ __launch_bounds__(256) void gate_argmax(const float* __restrict__ x,
                                                   const float* __restrict__ wg,
                                                   int* __restrict__ eidx) {
    int lane = threadIdx.x & 63, wv = threadIdx.x >> 6;
    int s = blockIdx.x * 4 + wv;
    const float* row = x + (size_t)s * DM;
    float acc[8] = {0.f,0.f,0.f,0.f,0.f,0.f,0.f,0.f};
    for (int kb = 0; kb < DM; kb += 256) {
        int k0 = kb + lane * 4;
        float4 xv = *(const float4*)(row + k0);
        const float* wr = wg + (size_t)k0 * NE;
        float xs[4] = {xv.x, xv.y, xv.z, xv.w};
#pragma unroll
        for (int c = 0; c < 4; ++c) {
            float4 w0 = *(const float4*)(wr + c * 8);
            float4 w1 = *(const float4*)(wr + c * 8 + 4);
            acc[0] += xs[c] * w0.x; acc[1] += xs[c] * w0.y;
            acc[2] += xs[c] * w0.z; acc[3] += xs[c] * w0.w;
            acc[4] += xs[c] * w1.x; acc[5] += xs[c] * w1.y;
            acc[6] += xs[c] * w1.z; acc[7] += xs[c] * w1.w;
        }
    }
#pragma unroll
    for (int off = 32; off > 0; off >>= 1)
#pragma unroll
        for (int e = 0; e < 8; ++e) acc[e] += __shfl_xor(acc[e], off, 64);
    if (lane == 0) {
        float best = acc[0]; int bi = 0;
#pragma unroll
        for (int e = 1; e < 8; ++e) if (acc[e] > best) { best = acc[e]; bi = e; }
        eidx[s] = bi;
    }
}

// ---------------- Kernel 2: slot assignment — single wave, prefetch-pipelined -------
__global__ __launch_bounds__(64) void scatter_slots(const int* __restrict__ eidx,
                                                    int* __restrict__ srcOf) {
    int lane = threadIdx.x;
    unsigned long long below = (lane == 0) ? 0ull : ((1ull << lane) - 1ull);
    for (int i = lane; i < NE * CAP; i += 64) srcOf[i] = -1;

    int cnt[NE] = {0,0,0,0,0,0,0,0};
    int e_cur = eidx[lane];
    for (int it = 0; it < S_TOK / 64; ++it) {
        int e_nxt = (it < S_TOK / 64 - 1) ? eidx[(it + 1) * 64 + lane] : 0;
        int s = it * 64 + lane;
#pragma unroll
        for (int ex = 0; ex < NE; ++ex) {
            unsigned long long m = __ballot(e_cur == ex);
            if (e_cur == ex) {
                int loc = cnt[ex] + __popcll(m & below);
                if (loc < CAP) srcOf[ex * CAP + loc] = s;
            }
            cnt[ex] += __popcll(m);
        }
        e_cur = e_nxt;
    }
}

// ---------------- Kernel 3: gather + f32->bf16, 128-row pre-swizzled A images -------
// A image per (e, mt 0..7, kt 0..31): 16 KB = [128 m][64 k] bf16, row 128 B,
// 16B chunk kg at byte m*128 + ((kg ^ (m&7))<<4).  gload_lds copies linearly.
__global__ __launch_bounds__(256) void pack_rows(const float* __restrict__ x,
                                                 const int* __restrict__ srcOf,
                                                 char* __restrict__ abuf) {
    int slot = blockIdx.x;               // e*1024 + c
    int e = slot >> 10, c = slot & 1023;
    int mt = c >> 7, m = c & 127;
    int src = srcOf[slot];
    int tid = threadIdx.x;
    int kt = tid >> 3, kg = tid & 7;     // kt 0..31, kg 0..7
    bf16x8 v = {};
    if (src >= 0) {
        const float4* p = (const float4*)(x + (size_t)src * DM + kt * 64 + kg * 8);
        float4 a = p[0], b = p[1];
        v = bf16x8{(bf16_t)a.x,(bf16_t)a.y,(bf16_t)a.z,(bf16_t)a.w,
                   (bf16_t)b.x,(bf16_t)b.y,(bf16_t)b.z,(bf16_t)b.w};
    }
    size_t img = (size_t)((e * 8 + mt) * 32 + kt) * 16384;
    int off = m * 128 + ((kg ^ (m & 7)) << 4);
    *(bf16x8*)(abuf + img + off) = v;
}

// ---- Kernel 4: 128x128x64 GEMM, 4 waves, single 32KB LDS buffer, ~3 blocks/CU ------
// m97 2-barrier structure with __syncthreads (compiler-fenced; raw s_barrier raced).
__global__ __launch_bounds__(256, 3) void moe_gemm(const char* __restrict__ abuf,
                                                   const float* __restrict__ we,
                                                   const float* __restrict__ be,
                                                   float* __restrict__ out) {
    __shared__ uint4 smem4[32768 / 16];           // A 16K @0 | B 16K @16384
    char* smem = (char*)smem4;

    int bid = blockIdx.x;
    int e  = bid & 7;                   // expert == XCD
    int r  = bid >> 3;
    int mt = r & 7;                     // 8 m-tiles of 128 (mt-major: B panel L2 reuse)
    int nt = r >> 3;                    // 64 n-tiles of 128
    int tid = threadIdx.x, lane = tid & 63, wv = tid >> 6;
    int wm = wv >> 1, wn = wv & 1;      // 2x2 wave grid -> 64x64 per wave
    int lr = lane & 15, g = lane >> 4;

    const char* aI = abuf + (size_t)((e * 8 + mt) * 32) * 16384;
    int q = tid >> 5;                   // k-octet 0..7
    int c = (tid & 31) * 4;             // n col base 0..124
    const float* bBase = we + (size_t)e * DM * DFF + (size_t)nt * 128 + c;

    f32x4 acc[4][4] = {};
    float4 bs[8];                       // B stage: k = q*8+j, n = c..c+3

    auto issueB = [&](int kt) {
        const float* bp = bBase + ((size_t)kt * 64 + q * 8) * DFF;
#pragma unroll
        for (int j = 0; j < 8; ++j)
            bs[j] = *(const float4*)(bp + (size_t)j * DFF);
    };
    auto writeB = [&]() {
#pragma unroll
        for (int i = 0; i < 4; ++i) {
            int n = c + i;
            bf16x8 w;
#pragma unroll
            for (int j = 0; j < 8; ++j) {
                float v = (i == 0) ? bs[j].x : (i == 1) ? bs[j].y
                        : (i == 2) ? bs[j].z : bs[j].w;
                w[j] = (bf16_t)v;
            }
            *(bf16x8*)(smem + 16384 + n * 128 + ((q ^ (n & 7)) << 4)) = w;
        }
    };
    auto stageA = [&](int kt) {
        const char* src = aI + (size_t)kt * 16384 + tid * 16;
        char* dst = smem + tid * 16;
#pragma unroll
        for (int i = 0; i < 4; ++i) load_lds16(src + i * 4096, dst + i * 4096);
    };

    // prologue: tile 0 staged
    issueB(0);
    stageA(0);
    writeB();                            // compiler auto-waits bs loads (counted)
    __syncthreads();

    for (int kt = 0; kt < 32; ++kt) {
        bool nl = (kt < 31);
        if (nl) issueB(kt + 1);          // L3 latency hides under this tile's MFMAs
        __builtin_amdgcn_sched_barrier(0);

        // ---- compute tile kt ----
        bf16x8 af[4][2];
#pragma unroll
        for (int mf = 0; mf < 4; ++mf) {
            int m = wm * 64 + mf * 16 + lr;
#pragma unroll
            for (int kk = 0; kk < 2; ++kk)
                af[mf][kk] = *(const bf16x8*)(smem + m * 128 + (((kk * 4 + g) ^ (m & 7)) << 4));
        }
#pragma unroll
        for (int nf = 0; nf < 4; ++nf) {
            int n = wn * 64 + nf * 16 + lr;
            bf16x8 bfr[2];
#pragma unroll
            for (int kk = 0; kk < 2; ++kk)
                bfr[kk] = *(const bf16x8*)(smem + 16384 + n * 128 + (((kk * 4 + g) ^ (n & 7)) << 4));
#pragma unroll
            for (int mf = 0; mf < 4; ++mf)
#pragma unroll
                for (int kk = 0; kk < 2; ++kk)
                    acc[mf][nf] = __builtin_amdgcn_mfma_f32_16x16x32_bf16(
                        af[mf][kk], bfr[kk], acc[mf][nf], 0, 0, 0);
        }

        if (nl) {
            __syncthreads();                         // all waves done reading tile kt
            stageA(kt + 1);
            writeB();                                // auto-counted wait on bs
            __syncthreads();                         // tile kt+1 staged & visible
        }
    }

    // epilogue: C/D layout col=lane&15, row=(lane>>4)*4+q
    int orow0 = e * CAP + mt * 128 + wm * 64 + g * 4;
    int ocol0 = nt * 128 + wn * 64 + lr;
#pragma unroll
    for (int nf = 0; nf < 4; ++nf) {
        int oc = ocol0 + nf * 16;
        float bias = be[(size_t)e * DFF + oc];
#pragma unroll
        for (int mf = 0; mf < 4; ++mf) {
            int orow = orow0 + mf * 16;
#pragma unroll
            for (int qq = 0; qq < 4; ++qq)
                out[(size_t)(orow + qq) * DFF + oc] = acc[mf][nf][qq] + bias;
        }
    }
}

// ---------------- launcher ----------------------------------------------------------
extern "C" void kernel_launch(void* const* d_in, const int* in_sizes, int n_in,
                              void* d_out, int out_size, void* d_ws, size_t ws_size,
                              hipStream_t stream) {
    const float* x  = (const float*)d_in[0];
    const float* wg = (const float*)d_in[1];
    const float* we = (const float*)d_in[2];
    const float* be = (const float*)d_in[3];
    float* out = (float*)d_out;

    size_t need = 65536 + (size_t)32 * 1048576;   // 64 KB meta + 32 MB abuf
    if (ws_size < need) return;

    int* eidx  = (int*)d_ws;
    int* srcOf = eidx + S_TOK;
    char* abuf = (char*)d_ws + 65536;

    gate_argmax<<<S_TOK / 4, 256, 0, stream>>>(x, wg, eidx);
    scatter_slots<<<1, 64, 0, stream>>>(eidx, srcOf);
    pack_rows<<<S_TOK, 256, 0, stream>>>(x, srcOf, abuf);
    moe_gemm<<<NE * 8 * 64, 256, 0, stream>>>(abuf, we, be, out);
}